// Round 8
// baseline (126.261 us; speedup 1.0000x reference)
//
#include <hip/hip_runtime.h>
#include <cstdint>

#define BB 4
#define LL 512
#define DD 64
#define HH 128
#define NEGV -1000000000.0f
#define NBLK 256
#define NTHR 1024
#define NACT 64   // blocks active during sinkhorn iterations (16 per batch, 32 rows each)

// ---------------------------------------------------------------------------
// Coherent (write-through / read-through) 8B accessors. Relaxed agent-scope
// atomics lower to global_load/store_dwordx2 sc0 sc1 — bypass the non-coherent
// per-XCD L2, hit the chip-coherent L3. ALL cross-block data moves through
// these, so barriers need NO buffer_wbl2/buffer_inv (round-5's 13us/barrier).
// ---------------------------------------------------------------------------
union U8 { unsigned long long u; float2 f; };

__device__ __forceinline__ float2 cload_f2(const float* p) {
    U8 v;
    v.u = __hip_atomic_load((const unsigned long long*)p,
                            __ATOMIC_RELAXED, __HIP_MEMORY_SCOPE_AGENT);
    return v.f;
}
__device__ __forceinline__ void cstore_f2(float* p, float2 x) {
    U8 v; v.f = x;
    __hip_atomic_store((unsigned long long*)p, v.u,
                       __ATOMIC_RELAXED, __HIP_MEMORY_SCOPE_AGENT);
}

// Light grid barrier: __syncthreads drains vmcnt (sc1 store ack = visible at
// L3), leader relaxed fetch_add + tight relaxed poll (poll load is a ~0.3us
// L3 RTT — self-pacing, no sleep for minimum wake latency); workgroup fences
// are waitcnt-only (compiler ordering, no cache maintenance).
__device__ __forceinline__ void grid_barrier(unsigned* cnt, unsigned target) {
    __builtin_amdgcn_fence(__ATOMIC_RELEASE, "workgroup");
    __syncthreads();
    if (threadIdx.x == 0) {
        __hip_atomic_fetch_add(cnt, 1u, __ATOMIC_RELAXED, __HIP_MEMORY_SCOPE_AGENT);
        while (__hip_atomic_load(cnt, __ATOMIC_RELAXED, __HIP_MEMORY_SCOPE_AGENT) < target) {}
    }
    __builtin_amdgcn_fence(__ATOMIC_ACQUIRE, "workgroup");
    __syncthreads();
}

__device__ __forceinline__ float hmax4(float4 v) {
    return fmaxf(fmaxf(v.x, v.y), fmaxf(v.z, v.w));
}

// __launch_bounds__(1024, 4): 4 waves/EU -> caps VGPR at 128 so the 16-wave
// block is schedulable as 1 block/CU.
__global__ __launch_bounds__(NTHR, 4) void mega(
    const float* __restrict__ etime, const int* __restrict__ etype,
    const float* __restrict__ x, const int* __restrict__ slens,
    const float* __restrict__ gum, const float* __restrict__ W1,
    const float* __restrict__ b1, const float* __restrict__ W2,
    const float* __restrict__ b2, float* __restrict__ out, float* __restrict__ ws)
{
    // LDS map (floats):
    //   [0,16384)      phase1: sp(8192)+sq(8192); then cbuf(16384); phase2: sla 32x512
    //   [16384,24576)  phase1: sx x-tiles [128][64]
    //   [16384,17408)  phase2: redm [2][512]
    //   [17408,18432)  phase2: reds [2][512]
    //   [18432,18944)  phase2: clse [512]
    //   [24576,24704)  sw2 [128]
    __shared__ float smem[24704];

    // ws words [0,256) = barrier counters (memset 1024B per replay):
    //   word 0: cntA (single all-256-block barrier after phase 1)
    //   word 32 + 32*b: per-batch iteration counters (128B apart, no false share)
    unsigned* cntA = (unsigned*)ws;
    float* laG   = ws + 256;                       // [4][512][512]
    float* cpkG  = laG + (size_t)BB * LL * LL;     // [2][4][16][512] x (m,s) pairs
    float* poutG = cpkG + (size_t)2 * BB * 16 * LL * 2; // [4][16][512] x (ty,tm)

    const int t = threadIdx.x;
    const int bx = blockIdx.x;

    // ============== Phase 1 (fused GEMV+GEMM): scores -> la0 ==================
    // Each block computes its OWN pi/pj tiles (redundant ~0.4us GEMV) straight
    // into swizzled LDS — no cross-block pi/pj handoff, no barrier before this.
    {
        float* sp  = smem;          // [64][128] swizzled pi tile
        float* sq  = smem + 8192;   // [64][128] swizzled pj tile
        float* sx  = smem + 16384;  // [128][64]: rows 0..63 x[i-tile], 64..127 x[j-tile]
        float* sw2 = smem + 24576;
        int jt = bx & 7, it8 = (bx >> 3) & 7, b = bx >> 6;
        int i0 = it8 << 6, j0 = jt << 6;

        // stage x tiles (plain cached loads — x is a read-only input)
        #pragma unroll
        for (int k = 0; k < 2; ++k) {
            int u = (k << 10) + t;          // 2048 float4 units
            int tile = u >> 10;             // 0: i-tile, 1: j-tile
            int v = u & 1023;
            int row = v >> 4, q4 = v & 15;
            const float* src = x + (size_t)(b * LL + (tile ? j0 : i0) + row) * DD + (q4 << 2);
            *(float4*)(sx + ((tile << 6) + row) * DD + (q4 << 2)) = *(const float4*)src;
        }
        if (t < HH) sw2[t] = W2[t];
        __syncthreads();

        // GEMV: pi = x@W1[:D]+b1, pj = x@W1[D:]; 4096 float4 outputs, 4/thread.
        // Same fma order (d ascending) as before -> identical values.
        #pragma unroll
        for (int o = 0; o < 4; ++o) {
            int u = (o << 10) + t;          // 0..4095
            int arr = u >> 11;              // 0: pi, 1: pj
            int v = u & 2047;
            int row = v >> 5, hq = v & 31;
            const float* wb = W1 + (size_t)(arr * DD) * HH + (hq << 2);
            float4 acc;
            if (arr == 0) acc = *(const float4*)(b1 + (hq << 2));
            else          acc = make_float4(0.f, 0.f, 0.f, 0.f);
            const float* xr = sx + ((arr << 6) + row) * DD;
            #pragma unroll 8
            for (int d = 0; d < DD; ++d) {
                float xv = xr[d];
                float4 w = *(const float4*)(wb + d * HH);
                acc.x = fmaf(xv, w.x, acc.x); acc.y = fmaf(xv, w.y, acc.y);
                acc.z = fmaf(xv, w.z, acc.z); acc.w = fmaf(xv, w.w, acc.w);
            }
            int dq = hq ^ ((row >> 2) & 7);    // XOR swizzle (matches GEMM reads)
            *(float4*)((arr ? sq : sp) + row * HH + (dq << 2)) = acc;
        }
        __syncthreads();

        // GEMM: h split into 4 groups of 8 hq; 256-thread group does 4x4 tile
        int hg = t >> 8, tt = t & 255;
        int w = tt >> 6, lane = tt & 63;
        int ti = ((w >> 1) << 3) + (lane >> 3);
        int tj = ((w & 1) << 3) + (lane & 7);
        int kti = ti & 7, ktj = tj & 7;

        float acc[4][4];
        #pragma unroll
        for (int a = 0; a < 4; ++a)
            #pragma unroll
            for (int c = 0; c < 4; ++c) acc[a][c] = 0.f;

        for (int hq = hg * 8; hq < hg * 8 + 8; ++hq) {
            float4 w4 = *(const float4*)(sw2 + (hq << 2));
            int offi = (hq ^ kti) << 2;
            int offj = (hq ^ ktj) << 2;
            float4 pa[4], pb[4];
            #pragma unroll
            for (int a = 0; a < 4; ++a) pa[a] = *(const float4*)(sp + (4*ti + a) * HH + offi);
            #pragma unroll
            for (int c = 0; c < 4; ++c) pb[c] = *(const float4*)(sq + (4*tj + c) * HH + offj);
            #pragma unroll
            for (int a = 0; a < 4; ++a) {
                #pragma unroll
                for (int c = 0; c < 4; ++c) {
                    float t0 = fmaxf(pa[a].x + pb[c].x, 0.f);
                    float t1 = fmaxf(pa[a].y + pb[c].y, 0.f);
                    float t2 = fmaxf(pa[a].z + pb[c].z, 0.f);
                    float t3 = fmaxf(pa[a].w + pb[c].w, 0.f);
                    float s = acc[a][c];
                    s += t0 * w4.x; s += t1 * w4.y; s += t2 * w4.z; s += t3 * w4.w;
                    acc[a][c] = s;
                }
            }
        }
        __syncthreads();                      // done with sp/sq
        float* cbuf = smem;                   // alias: [4 groups][256 tt][16]
        #pragma unroll
        for (int a = 0; a < 4; ++a)
            #pragma unroll
            for (int c = 0; c < 4; ++c)
                cbuf[(((hg << 8) + tt) << 4) + (a << 2) + c] = acc[a][c];
        __syncthreads();

        int tt2 = t >> 2, a2 = t & 3;
        int w2_ = tt2 >> 6, lane2 = tt2 & 63;
        int ti2 = ((w2_ >> 1) << 3) + (lane2 >> 3);
        int tj2 = ((w2_ & 1) << 3) + (lane2 & 7);
        float4 o = make_float4(0.f, 0.f, 0.f, 0.f);
        #pragma unroll
        for (int g = 0; g < 4; ++g) {
            float4 pp = *(const float4*)(cbuf + (((g << 8) + tt2) << 4) + (a2 << 2));
            o.x += pp.x; o.y += pp.y; o.z += pp.z; o.w += pp.w;
        }
        int sl = slens[b];
        float bb2 = b2[0];
        int ig = i0 + 4 * ti2 + a2;
        int jb = j0 + 4 * tj2;
        float4 g4 = *(const float4*)(gum + ((size_t)(b * LL + ig)) * LL + jb);
        bool iv = ig < sl;
        float4 res;
        res.x = (iv && (jb + 0) < sl) ? (o.x + bb2 + g4.x) * 2.0f : NEGV;
        res.y = (iv && (jb + 1) < sl) ? (o.y + bb2 + g4.y) * 2.0f : NEGV;
        res.z = (iv && (jb + 2) < sl) ? (o.z + bb2 + g4.z) * 2.0f : NEGV;
        res.w = (iv && (jb + 3) < sl) ? (o.w + bb2 + g4.w) * 2.0f : NEGV;
        float* lap = laG + ((size_t)(b * LL + ig)) * LL + jb;
        cstore_f2(lap,     make_float2(res.x, res.y));
        cstore_f2(lap + 2, make_float2(res.z, res.w));
    }
    grid_barrier(cntA, NBLK);                 // the ONLY all-block barrier

    // ===================== Phase 2: 10 Sinkhorn iterations =====================
    if (bx >= NACT) return;

    const int b2i = bx >> 4;
    const int stripe = bx & 15;
    const int r0 = stripe << 5;               // 32 rows per active block
    unsigned* cntB = (unsigned*)ws + 32 + (b2i << 5);  // per-batch counter
    float* sla  = smem;                       // [32][512] row-normed R (UNMASKED)
    float* redm = smem + 16384;               // [2][512]
    float* reds = smem + 17408;               // [2][512]
    float* clse = smem + 18432;               // [512] current col-LSE
    const int sl_a = slens[b2i];
    float tyv = 0.f, tmv = 0.f;

    {
        const float* src = laG + (((size_t)(b2i << 9) + r0) << 9);
        #pragma unroll
        for (int k = 0; k < 8; ++k) {
            int u = (k << 10) + t;             // 8192 8B units = 32x512 floats
            float2 v = cload_f2(src + (u << 1));
            *(float2*)(sla + (u << 1)) = v;
        }
        if (t < 512) clse[t] = 0.f;            // iter-0: subtract nothing
        __syncthreads();
    }

    for (int it = 0; it < 10; ++it) {
        const int par = it & 1;
        const int last = (it == 9);
        {
            // ---- fused row pass: read (mask ? NEG : R - clse), LSE, write R' --
            // Value stream identical to the reference: masked input, lse =
            // m + log(s) (fp32 NEG absorption), output UNMASKED (invalid rows
            // become exact 0s, which the col pass must see).
            int r = t >> 5, cq = t & 31;
            int grow = r0 + r;
            bool ivR = grow < sl_a;
            float4 v[4];
            #pragma unroll
            for (int k = 0; k < 4; ++k) {
                int cb = (cq + (k << 5)) << 2;
                float4 a = *(float4*)(sla + (r << 9) + cb);
                float4 l = *(const float4*)(clse + cb);
                v[k].x = (ivR && (cb + 0) < sl_a) ? a.x - l.x : NEGV;
                v[k].y = (ivR && (cb + 1) < sl_a) ? a.y - l.y : NEGV;
                v[k].z = (ivR && (cb + 2) < sl_a) ? a.z - l.z : NEGV;
                v[k].w = (ivR && (cb + 3) < sl_a) ? a.w - l.w : NEGV;
            }
            float m = fmaxf(fmaxf(hmax4(v[0]), hmax4(v[1])), fmaxf(hmax4(v[2]), hmax4(v[3])));
            #pragma unroll
            for (int off = 16; off; off >>= 1) m = fmaxf(m, __shfl_xor(m, off));
            float s = 0.f;
            #pragma unroll
            for (int k = 0; k < 4; ++k)
                s += __expf(v[k].x - m) + __expf(v[k].y - m) + __expf(v[k].z - m) + __expf(v[k].w - m);
            #pragma unroll
            for (int off = 16; off; off >>= 1) s += __shfl_xor(s, off);
            float lse = m + __logf(s);
            #pragma unroll
            for (int k = 0; k < 4; ++k) {
                v[k].x -= lse; v[k].y -= lse; v[k].z -= lse; v[k].w -= lse;
                *(float4*)(sla + (r << 9) + ((cq + (k << 5)) << 2)) = v[k];
            }
            __syncthreads();                                           // S1

            // ---- column partials over 32 rows: (m,s) per half, pre-combined --
            int c = t & 511, half = t >> 9;
            float vv[16];
            #pragma unroll
            for (int rr = 0; rr < 16; ++rr) vv[rr] = sla[(((half << 4) + rr) << 9) + c];
            float mp = vv[0];
            #pragma unroll
            for (int rr = 1; rr < 16; ++rr) mp = fmaxf(mp, vv[rr]);
            float spv = 0.f;
            #pragma unroll
            for (int rr = 0; rr < 16; ++rr) spv += __expf(vv[rr] - mp);
            redm[(half << 9) + c] = mp;
            reds[(half << 9) + c] = spv;
            __syncthreads();                                           // S2
            if (half == 0) {
                float m1 = redm[512 + c], s1 = reds[512 + c];
                float M = fmaxf(mp, m1);
                float S = fmaf(spv, __expf(mp - M), s1 * __expf(m1 - M));
                cstore_f2(cpkG + (size_t)(((((par * BB) + b2i) << 4) + stripe) * LL + c) * 2,
                          make_float2(M, S));
            }
        }
        grid_barrier(cntB, (it + 1) * 16);                             // S3,S4
        {
            // ---- flat combine: 512 threads each read all 16 (m,s) partials ---
            if (t < 512) {
                const float* pB = cpkG + (size_t)((((par * BB) + b2i) << 4) * LL) * 2;
                float mreg[16], sreg[16];
                #pragma unroll
                for (int g = 0; g < 16; ++g) {
                    float2 ms = cload_f2(pB + (size_t)(g * LL + t) * 2);
                    mreg[g] = ms.x; sreg[g] = ms.y;
                }
                float M = mreg[0];
                #pragma unroll
                for (int g = 1; g < 16; ++g) M = fmaxf(M, mreg[g]);
                float S = 0.f;
                #pragma unroll
                for (int g = 0; g < 16; ++g)
                    S = fmaf(sreg[g], __expf(mreg[g] - M), S);
                clse[t] = M + __logf(S);
            }
            __syncthreads();                                           // S5

            if (last) {
                // final: perm = mask ? 0 : exp(R - clse); fused column sums
                int r = t >> 5, cq = t & 31;
                int grow = r0 + r;
                bool ivR = grow < sl_a;
                float etf = (float)etype[(b2i << 9) + grow];
                float etv = etime[(b2i << 9) + grow];
                float4 p[4];
                #pragma unroll
                for (int k = 0; k < 4; ++k) {
                    int cb = (cq + (k << 5)) << 2;
                    float4 v = *(float4*)(sla + (r << 9) + cb);
                    float4 l = *(const float4*)(clse + cb);
                    float4 q;
                    q.x = (ivR && (cb + 0) < sl_a) ? __expf(v.x - l.x) : 0.f;
                    q.y = (ivR && (cb + 1) < sl_a) ? __expf(v.y - l.y) : 0.f;
                    q.z = (ivR && (cb + 2) < sl_a) ? __expf(v.z - l.z) : 0.f;
                    q.w = (ivR && (cb + 3) < sl_a) ? __expf(v.w - l.w) : 0.f;
                    p[k] = q;
                    *(float4*)(out + 2 * BB * LL + (((size_t)(b2i << 9) + grow) << 9) + cb) = q;
                }
                // type-weighted column partial (transpose via sla)
                #pragma unroll
                for (int k = 0; k < 4; ++k) {
                    int cb = (cq + (k << 5)) << 2;
                    *(float4*)(sla + (r << 9) + cb) =
                        make_float4(p[k].x * etf, p[k].y * etf, p[k].z * etf, p[k].w * etf);
                }
                __syncthreads();
                {
                    int c2 = t & 511, h2 = t >> 9;
                    float sA = 0.f;
                    #pragma unroll
                    for (int rr = 0; rr < 16; ++rr) sA += sla[(((h2 << 4) + rr) << 9) + c2];
                    redm[(h2 << 9) + c2] = sA;
                }
                __syncthreads();
                if (t < 512) tyv = redm[t] + redm[512 + t];
                __syncthreads();
                // time-weighted column partial
                #pragma unroll
                for (int k = 0; k < 4; ++k) {
                    int cb = (cq + (k << 5)) << 2;
                    *(float4*)(sla + (r << 9) + cb) =
                        make_float4(p[k].x * etv, p[k].y * etv, p[k].z * etv, p[k].w * etv);
                }
                __syncthreads();
                {
                    int c2 = t & 511, h2 = t >> 9;
                    float sB = 0.f;
                    #pragma unroll
                    for (int rr = 0; rr < 16; ++rr) sB += sla[(((h2 << 4) + rr) << 9) + c2];
                    reds[(h2 << 9) + c2] = sB;
                }
                __syncthreads();
                if (t < 512) {
                    tmv = reds[t] + reds[512 + t];
                    cstore_f2(poutG + (size_t)(((b2i << 4) + stripe) * LL + t) * 2,
                              make_float2(tyv, tmv));
                }
            }
        }
    }
    grid_barrier(cntB, 11 * 16);

    // ===================== Phase 3: combine output partials (per batch) ========
    if (t < 32) {
        int c = (stripe << 5) + t;
        float a = 0.f, d = 0.f;
        #pragma unroll
        for (int s = 0; s < 16; ++s) {
            float2 p = cload_f2(poutG + (size_t)(((b2i << 4) + s) * LL + c) * 2);
            a += p.x; d += p.y;
        }
        out[(b2i << 9) + c] = a;                 // types_permed
        out[BB * LL + (b2i << 9) + c] = d;       // times_permed
    }
}

extern "C" void kernel_launch(void* const* d_in, const int* in_sizes, int n_in,
                              void* d_out, int out_size, void* d_ws, size_t ws_size,
                              hipStream_t stream)
{
    const float* etime = (const float*)d_in[0];
    const int*   etype = (const int*)d_in[1];
    const float* x     = (const float*)d_in[2];
    const int*   slens = (const int*)d_in[3];
    const float* gum   = (const float*)d_in[4];
    const float* W1    = (const float*)d_in[5];
    const float* b1    = (const float*)d_in[6];
    const float* W2    = (const float*)d_in[7];
    const float* b2    = (const float*)d_in[8];
    float* out = (float*)d_out;
    float* wsf = (float*)d_ws;

    // reset all barrier counters (words 0..255) deterministically per replay
    hipMemsetAsync(d_ws, 0, 1024, stream);

    void* args[] = {(void*)&etime, (void*)&etype, (void*)&x, (void*)&slens, (void*)&gum,
                    (void*)&W1, (void*)&b1, (void*)&W2, (void*)&b2, (void*)&out, (void*)&wsf};
    hipError_t err = hipLaunchCooperativeKernel((const void*)mega, dim3(NBLK), dim3(NTHR),
                                                args, 0, stream);
    if (err != hipSuccess) {
        // 256 blocks x 1024 thr, ~97KB LDS -> exactly 1 block/CU on 256 CUs.
        mega<<<NBLK, NTHR, 0, stream>>>(etime, etype, x, slens, gum, W1, b1, W2, b2, out, wsf);
    }
}

// Round 9
// 112.821 us; speedup vs baseline: 1.1191x; 1.1191x over previous
//
#include <hip/hip_runtime.h>
#include <cstdint>

#define BB 4
#define LL 512
#define DD 64
#define HH 128
#define NEGV -1000000000.0f
#define NBLK 256
#define NTHR 1024
#define NACT 64   // blocks active during sinkhorn iterations (16 per batch, 32 rows each)

// ---------------------------------------------------------------------------
// Coherent (write-through / read-through) 8B accessors. Relaxed agent-scope
// atomics lower to global_load/store_dwordx2 sc0 sc1 — bypass the non-coherent
// per-XCD L2, hit the chip-coherent L3. ALL cross-block data moves through
// these, so no buffer_wbl2/buffer_inv is ever needed.
// ---------------------------------------------------------------------------
union U8 { unsigned long long u; float2 f; };

__device__ __forceinline__ float2 cload_f2(const float* p) {
    U8 v;
    v.u = __hip_atomic_load((const unsigned long long*)p,
                            __ATOMIC_RELAXED, __HIP_MEMORY_SCOPE_AGENT);
    return v.f;
}
__device__ __forceinline__ void cstore_f2(float* p, float2 x) {
    U8 v; v.f = x;
    __hip_atomic_store((unsigned long long*)p, v.u,
                       __ATOMIC_RELAXED, __HIP_MEMORY_SCOPE_AGENT);
}

// Point-to-point flag sync (replaces all grid barriers / counters):
//   writer: data cstores -> fence(release,workgroup) [per-wave vmcnt(0) drain,
//           sc1 store ack = data in L3] -> __syncthreads -> set_flag
//   reader: poll flag (relaxed, straight to L3) -> control-dep -> data loads
// Flags are write-once per replay (indexed by event), zeroed by the memset
// node, so there is no reset race and no RMW contention anywhere.
__device__ __forceinline__ void set_flag(unsigned* f) {
    __hip_atomic_store(f, 1u, __ATOMIC_RELAXED, __HIP_MEMORY_SCOPE_AGENT);
}
__device__ __forceinline__ void wait_flag(unsigned* f) {
    while (__hip_atomic_load(f, __ATOMIC_RELAXED, __HIP_MEMORY_SCOPE_AGENT) == 0u) {}
}

__device__ __forceinline__ float hmax4(float4 v) {
    return fmaxf(fmaxf(v.x, v.y), fmaxf(v.z, v.w));
}

// Flag word indices inside ws (all < 2048; memset 8192 B per replay)
#define FLG_GEMV 0        // [256]  : gemv block bx done (rows bx*8..+8 of pi&pj)
#define FLG_TILE 256      // [256]  : la tile (b,it8,jt) done
#define FLG_ITER 512      // [640]  : iter partial (b,it,stripe) stored
#define FLG_POUT 1152     // [64]   : pout (b,stripe) stored

__global__ __launch_bounds__(NTHR, 4) void mega(
    const float* __restrict__ etime, const int* __restrict__ etype,
    const float* __restrict__ x, const int* __restrict__ slens,
    const float* __restrict__ gum, const float* __restrict__ W1,
    const float* __restrict__ b1, const float* __restrict__ W2,
    const float* __restrict__ b2, float* __restrict__ out, float* __restrict__ ws)
{
    // LDS map (floats):
    //   [0,16384)      phaseB: sp(8192)+sq(8192); then cbuf(16384); phaseC: sla 32x512
    //   [16384,17408)  redm [2][512]
    //   [17408,18432)  reds [2][512]
    //   [18432,18944)  clse [512]
    //   [18944,19072)  sw2  [128]
    __shared__ float smem[19072];

    unsigned* flg = (unsigned*)ws;
    float* piG   = ws + 2048;                      // [2048][128]
    float* pjG   = piG + BB * LL * HH;             // [2048][128]
    float* laG   = pjG + BB * LL * HH;             // [4][512][512]
    float* cpkG  = laG + (size_t)BB * LL * LL;     // [2][4][16][512] x (m,s) pairs
    float* poutG = cpkG + (size_t)2 * BB * 16 * LL * 2; // [4][16][512] x (ty,tm)

    const int t = threadIdx.x;
    const int bx = blockIdx.x;

    // ============== Phase A: GEMV — block bx computes rows bx*8..+8 ===========
    // pi = x@W1[:D]+b1 ; pj = x@W1[D:]. 1024 threads -> 1024 f2 outputs
    // (8 rows x 2 arrays x 64 h-pairs). Same per-output fma order (d ascending)
    // as rounds 3-7.
    {
        int arr = t >> 9;                  // 0: pi, 1: pj
        int row = (t >> 6) & 7;            // 0..7
        int h0  = (t & 63) << 1;
        int grow = (bx << 3) + row;        // global row 0..2047
        const float* xr = x + (size_t)grow * DD;
        const float* wb = W1 + (size_t)(arr * DD) * HH + h0;
        float a0 = arr ? 0.f : b1[h0];
        float a1 = arr ? 0.f : b1[h0 + 1];
        #pragma unroll 8
        for (int d = 0; d < DD; ++d) {
            float xv = xr[d];
            float2 w = *(const float2*)(wb + d * HH);
            a0 = fmaf(xv, w.x, a0);
            a1 = fmaf(xv, w.y, a1);
        }
        cstore_f2((arr ? pjG : piG) + (size_t)grow * HH + h0, make_float2(a0, a1));
        __builtin_amdgcn_fence(__ATOMIC_RELEASE, "workgroup");
        __syncthreads();
        if (t == 0) set_flag(flg + FLG_GEMV + bx);
    }

    // ============== Phase B: scores -> la0 (masked, /tau) ======================
    {
        float* sp  = smem;
        float* sq  = smem + 8192;
        float* sw2 = smem + 18944;
        int jt = bx & 7, it8 = (bx >> 3) & 7, b = bx >> 6;
        int i0 = it8 << 6, j0 = jt << 6;
        int rowb = b * LL + i0, colb = b * LL + j0;

        // wait for the 8 gemv blocks covering the pi band and 8 for the pj band
        if (t < 8)              wait_flag(flg + FLG_GEMV + (b << 6) + (it8 << 3) + t);
        else if (t < 16)        wait_flag(flg + FLG_GEMV + (b << 6) + (jt << 3) + (t - 8));
        if (t < HH) sw2[t] = W2[t];
        __syncthreads();

        // stage pi/pj tiles (coherent 8B loads), XOR-swizzled into LDS
        #pragma unroll
        for (int k = 0; k < 8; ++k) {
            int idx = (k << 10) + t;        // 0..8191 8B units
            int buf = idx >> 12;            // 0: pi->sp, 1: pj->sq
            int u   = idx & 4095;
            int row = u >> 6;               // 0..63
            int du  = u & 63;               // h0 = du*2
            int q   = du >> 1;
            int hi  = du & 1;
            int dq  = q ^ ((row >> 2) & 7);
            const float* src = (buf ? pjG + (size_t)(colb + row) * HH
                                    : piG + (size_t)(rowb + row) * HH) + (du << 1);
            float2 v = cload_f2(src);
            float* dst = (buf ? sq : sp) + row * HH + (dq << 2) + (hi << 1);
            *(float2*)dst = v;
        }
        __syncthreads();

        // GEMM: h split into 4 groups of 8 hq; 256-thread group does 4x4 tile
        int hg = t >> 8, tt = t & 255;
        int w = tt >> 6, lane = tt & 63;
        int ti = ((w >> 1) << 3) + (lane >> 3);
        int tj = ((w & 1) << 3) + (lane & 7);
        int kti = ti & 7, ktj = tj & 7;

        float acc[4][4];
        #pragma unroll
        for (int a = 0; a < 4; ++a)
            #pragma unroll
            for (int c = 0; c < 4; ++c) acc[a][c] = 0.f;

        for (int hq = hg * 8; hq < hg * 8 + 8; ++hq) {
            float4 w4 = *(const float4*)(sw2 + (hq << 2));
            int offi = (hq ^ kti) << 2;
            int offj = (hq ^ ktj) << 2;
            float4 pa[4], pb[4];
            #pragma unroll
            for (int a = 0; a < 4; ++a) pa[a] = *(const float4*)(sp + (4*ti + a) * HH + offi);
            #pragma unroll
            for (int c = 0; c < 4; ++c) pb[c] = *(const float4*)(sq + (4*tj + c) * HH + offj);
            #pragma unroll
            for (int a = 0; a < 4; ++a) {
                #pragma unroll
                for (int c = 0; c < 4; ++c) {
                    float t0 = fmaxf(pa[a].x + pb[c].x, 0.f);
                    float t1 = fmaxf(pa[a].y + pb[c].y, 0.f);
                    float t2 = fmaxf(pa[a].z + pb[c].z, 0.f);
                    float t3 = fmaxf(pa[a].w + pb[c].w, 0.f);
                    float s = acc[a][c];
                    s += t0 * w4.x; s += t1 * w4.y; s += t2 * w4.z; s += t3 * w4.w;
                    acc[a][c] = s;
                }
            }
        }
        __syncthreads();                      // done with sp/sq
        float* cbuf = smem;                   // alias: [4 groups][256 tt][16]
        #pragma unroll
        for (int a = 0; a < 4; ++a)
            #pragma unroll
            for (int c = 0; c < 4; ++c)
                cbuf[(((hg << 8) + tt) << 4) + (a << 2) + c] = acc[a][c];
        __syncthreads();

        int tt2 = t >> 2, a2 = t & 3;
        int w2_ = tt2 >> 6, lane2 = tt2 & 63;
        int ti2 = ((w2_ >> 1) << 3) + (lane2 >> 3);
        int tj2 = ((w2_ & 1) << 3) + (lane2 & 7);
        float4 o = make_float4(0.f, 0.f, 0.f, 0.f);
        #pragma unroll
        for (int g = 0; g < 4; ++g) {
            float4 pp = *(const float4*)(cbuf + (((g << 8) + tt2) << 4) + (a2 << 2));
            o.x += pp.x; o.y += pp.y; o.z += pp.z; o.w += pp.w;
        }
        int sl = slens[b];
        float bb2 = b2[0];
        int ig = i0 + 4 * ti2 + a2;
        int jb = j0 + 4 * tj2;
        float4 g4 = *(const float4*)(gum + ((size_t)(b * LL + ig)) * LL + jb);
        bool iv = ig < sl;
        float4 res;
        res.x = (iv && (jb + 0) < sl) ? (o.x + bb2 + g4.x) * 2.0f : NEGV;
        res.y = (iv && (jb + 1) < sl) ? (o.y + bb2 + g4.y) * 2.0f : NEGV;
        res.z = (iv && (jb + 2) < sl) ? (o.z + bb2 + g4.z) * 2.0f : NEGV;
        res.w = (iv && (jb + 3) < sl) ? (o.w + bb2 + g4.w) * 2.0f : NEGV;
        float* lap = laG + ((size_t)(b * LL + ig)) * LL + jb;
        cstore_f2(lap,     make_float2(res.x, res.y));
        cstore_f2(lap + 2, make_float2(res.z, res.w));
        __builtin_amdgcn_fence(__ATOMIC_RELEASE, "workgroup");
        __syncthreads();
        if (t == 0) set_flag(flg + FLG_TILE + (b << 6) + (it8 << 3) + jt);
    }

    // ===================== Phase C: 10 Sinkhorn iterations =====================
    if (bx >= NACT) return;

    const int b2i = bx >> 4;
    const int stripe = bx & 15;
    const int r0 = stripe << 5;               // 32 rows per active block
    float* sla  = smem;                       // [32][512] row-normed R (UNMASKED)
    float* redm = smem + 16384;               // [2][512]
    float* reds = smem + 17408;               // [2][512]
    float* clse = smem + 18432;               // [512] current col-LSE
    const int sl_a = slens[b2i];
    float tyv = 0.f, tmv = 0.f;

    {
        // need the 8 la tiles of this stripe's row band (it8 = stripe>>1)
        if (t < 8) wait_flag(flg + FLG_TILE + (b2i << 6) + ((stripe >> 1) << 3) + t);
        __syncthreads();
        const float* src = laG + (((size_t)(b2i << 9) + r0) << 9);
        #pragma unroll
        for (int k = 0; k < 8; ++k) {
            int u = (k << 10) + t;             // 8192 8B units = 32x512 floats
            float2 v = cload_f2(src + (u << 1));
            *(float2*)(sla + (u << 1)) = v;
        }
        if (t < 512) clse[t] = 0.f;            // iter-0: subtract nothing
        __syncthreads();
    }

    for (int it = 0; it < 10; ++it) {
        const int par = it & 1;
        const int last = (it == 9);
        {
            // ---- fused row pass: read (mask ? NEG : R - clse), LSE, write R' --
            int r = t >> 5, cq = t & 31;
            int grow = r0 + r;
            bool ivR = grow < sl_a;
            float4 v[4];
            #pragma unroll
            for (int k = 0; k < 4; ++k) {
                int cb = (cq + (k << 5)) << 2;
                float4 a = *(float4*)(sla + (r << 9) + cb);
                float4 l = *(const float4*)(clse + cb);
                v[k].x = (ivR && (cb + 0) < sl_a) ? a.x - l.x : NEGV;
                v[k].y = (ivR && (cb + 1) < sl_a) ? a.y - l.y : NEGV;
                v[k].z = (ivR && (cb + 2) < sl_a) ? a.z - l.z : NEGV;
                v[k].w = (ivR && (cb + 3) < sl_a) ? a.w - l.w : NEGV;
            }
            float m = fmaxf(fmaxf(hmax4(v[0]), hmax4(v[1])), fmaxf(hmax4(v[2]), hmax4(v[3])));
            #pragma unroll
            for (int off = 16; off; off >>= 1) m = fmaxf(m, __shfl_xor(m, off));
            float s = 0.f;
            #pragma unroll
            for (int k = 0; k < 4; ++k)
                s += __expf(v[k].x - m) + __expf(v[k].y - m) + __expf(v[k].z - m) + __expf(v[k].w - m);
            #pragma unroll
            for (int off = 16; off; off >>= 1) s += __shfl_xor(s, off);
            float lse = m + __logf(s);        // NEG-absorption preserved in fp32
            #pragma unroll
            for (int k = 0; k < 4; ++k) {
                v[k].x -= lse; v[k].y -= lse; v[k].z -= lse; v[k].w -= lse;
                *(float4*)(sla + (r << 9) + ((cq + (k << 5)) << 2)) = v[k];
            }
            __syncthreads();                                           // S1

            // ---- column partials over 32 rows: (m,s) per half, pre-combined --
            int c = t & 511, half = t >> 9;
            float vv[16];
            #pragma unroll
            for (int rr = 0; rr < 16; ++rr) vv[rr] = sla[(((half << 4) + rr) << 9) + c];
            float mp = vv[0];
            #pragma unroll
            for (int rr = 1; rr < 16; ++rr) mp = fmaxf(mp, vv[rr]);
            float spv = 0.f;
            #pragma unroll
            for (int rr = 0; rr < 16; ++rr) spv += __expf(vv[rr] - mp);
            redm[(half << 9) + c] = mp;
            reds[(half << 9) + c] = spv;
            __syncthreads();                                           // S2
            if (half == 0) {
                float m1 = redm[512 + c], s1 = reds[512 + c];
                float M = fmaxf(mp, m1);
                float S = fmaf(spv, __expf(mp - M), s1 * __expf(m1 - M));
                cstore_f2(cpkG + (size_t)(((((par * BB) + b2i) << 4) + stripe) * LL + c) * 2,
                          make_float2(M, S));
            }
            __builtin_amdgcn_fence(__ATOMIC_RELEASE, "workgroup");
            __syncthreads();                                           // S3
            if (t == 0) set_flag(flg + FLG_ITER + (((b2i * 10) + it) << 4) + stripe);
            if (t < 16) wait_flag(flg + FLG_ITER + (((b2i * 10) + it) << 4) + t);
            __syncthreads();                                           // S4
        }
        {
            // ---- flat combine: 512 threads each read all 16 (m,s) partials ---
            if (t < 512) {
                const float* pB = cpkG + (size_t)((((par * BB) + b2i) << 4) * LL) * 2;
                float mreg[16], sreg[16];
                #pragma unroll
                for (int g = 0; g < 16; ++g) {
                    float2 ms = cload_f2(pB + (size_t)(g * LL + t) * 2);
                    mreg[g] = ms.x; sreg[g] = ms.y;
                }
                float M = mreg[0];
                #pragma unroll
                for (int g = 1; g < 16; ++g) M = fmaxf(M, mreg[g]);
                float S = 0.f;
                #pragma unroll
                for (int g = 0; g < 16; ++g)
                    S = fmaf(sreg[g], __expf(mreg[g] - M), S);
                clse[t] = M + __logf(S);
            }
            __syncthreads();                                           // S5

            if (last) {
                // final: perm = mask ? 0 : exp(R - clse); fused column sums
                int r = t >> 5, cq = t & 31;
                int grow = r0 + r;
                bool ivR = grow < sl_a;
                float etf = (float)etype[(b2i << 9) + grow];
                float etv = etime[(b2i << 9) + grow];
                float4 p[4];
                #pragma unroll
                for (int k = 0; k < 4; ++k) {
                    int cb = (cq + (k << 5)) << 2;
                    float4 v = *(float4*)(sla + (r << 9) + cb);
                    float4 l = *(const float4*)(clse + cb);
                    float4 q;
                    q.x = (ivR && (cb + 0) < sl_a) ? __expf(v.x - l.x) : 0.f;
                    q.y = (ivR && (cb + 1) < sl_a) ? __expf(v.y - l.y) : 0.f;
                    q.z = (ivR && (cb + 2) < sl_a) ? __expf(v.z - l.z) : 0.f;
                    q.w = (ivR && (cb + 3) < sl_a) ? __expf(v.w - l.w) : 0.f;
                    p[k] = q;
                    *(float4*)(out + 2 * BB * LL + (((size_t)(b2i << 9) + grow) << 9) + cb) = q;
                }
                // type-weighted column partial (transpose via sla)
                #pragma unroll
                for (int k = 0; k < 4; ++k) {
                    int cb = (cq + (k << 5)) << 2;
                    *(float4*)(sla + (r << 9) + cb) =
                        make_float4(p[k].x * etf, p[k].y * etf, p[k].z * etf, p[k].w * etf);
                }
                __syncthreads();
                {
                    int c2 = t & 511, h2 = t >> 9;
                    float sA = 0.f;
                    #pragma unroll
                    for (int rr = 0; rr < 16; ++rr) sA += sla[(((h2 << 4) + rr) << 9) + c2];
                    redm[(h2 << 9) + c2] = sA;
                }
                __syncthreads();
                if (t < 512) tyv = redm[t] + redm[512 + t];
                __syncthreads();
                // time-weighted column partial
                #pragma unroll
                for (int k = 0; k < 4; ++k) {
                    int cb = (cq + (k << 5)) << 2;
                    *(float4*)(sla + (r << 9) + cb) =
                        make_float4(p[k].x * etv, p[k].y * etv, p[k].z * etv, p[k].w * etv);
                }
                __syncthreads();
                {
                    int c2 = t & 511, h2 = t >> 9;
                    float sB = 0.f;
                    #pragma unroll
                    for (int rr = 0; rr < 16; ++rr) sB += sla[(((h2 << 4) + rr) << 9) + c2];
                    reds[(h2 << 9) + c2] = sB;
                }
                __syncthreads();
                if (t < 512) {
                    tmv = reds[t] + reds[512 + t];
                    cstore_f2(poutG + (size_t)(((b2i << 4) + stripe) * LL + t) * 2,
                              make_float2(tyv, tmv));
                }
                __builtin_amdgcn_fence(__ATOMIC_RELEASE, "workgroup");
                __syncthreads();
                if (t == 0) set_flag(flg + FLG_POUT + (b2i << 4) + stripe);
            }
        }
    }

    // ===================== Phase D: combine output partials (per batch) ========
    if (t < 16) wait_flag(flg + FLG_POUT + (b2i << 4) + t);
    __syncthreads();
    if (t < 32) {
        int c = (stripe << 5) + t;
        float a = 0.f, d = 0.f;
        #pragma unroll
        for (int s = 0; s < 16; ++s) {
            float2 p = cload_f2(poutG + (size_t)(((b2i << 4) + s) * LL + c) * 2);
            a += p.x; d += p.y;
        }
        out[(b2i << 9) + c] = a;                 // types_permed
        out[BB * LL + (b2i << 9) + c] = d;       // times_permed
    }
}

extern "C" void kernel_launch(void* const* d_in, const int* in_sizes, int n_in,
                              void* d_out, int out_size, void* d_ws, size_t ws_size,
                              hipStream_t stream)
{
    const float* etime = (const float*)d_in[0];
    const int*   etype = (const int*)d_in[1];
    const float* x     = (const float*)d_in[2];
    const int*   slens = (const int*)d_in[3];
    const float* gum   = (const float*)d_in[4];
    const float* W1    = (const float*)d_in[5];
    const float* b1    = (const float*)d_in[6];
    const float* W2    = (const float*)d_in[7];
    const float* b2    = (const float*)d_in[8];
    float* out = (float*)d_out;
    float* wsf = (float*)d_ws;

    // zero all flag words (ws words [0,2048)) deterministically per replay
    hipMemsetAsync(d_ws, 0, 8192, stream);

    void* args[] = {(void*)&etime, (void*)&etype, (void*)&x, (void*)&slens, (void*)&gum,
                    (void*)&W1, (void*)&b1, (void*)&W2, (void*)&b2, (void*)&out, (void*)&wsf};
    hipError_t err = hipLaunchCooperativeKernel((const void*)mega, dim3(NBLK), dim3(NTHR),
                                                args, 0, stream);
    if (err != hipSuccess) {
        // 256 blocks x 1024 thr, ~76KB LDS -> 1 block/CU on 256 CUs (co-resident;
        // flag deps only ever point from lower-indexed work that is resident).
        mega<<<NBLK, NTHR, 0, stream>>>(etime, etype, x, slens, gum, W1, b1, W2, b2, out, wsf);
    }
}